// Round 1
// baseline (163.621 us; speedup 1.0000x reference)
//
#include <hip/hip_runtime.h>
#include <hip/hip_bf16.h>

// Problem constants
constexpr int Dd = 1024;           // feature dim
constexpr int Tt = 2048;           // sequence length
constexpr int Bb = 4;              // batch
constexpr int Rr = Bb * Tt;        // GEMM rows = 8192
constexpr int NCHUNK = 32;         // scan chunks
constexpr int CLEN = Tt / NCHUNK;  // 64 steps per chunk

typedef __attribute__((ext_vector_type(4))) float f32x4;
typedef __attribute__((ext_vector_type(8))) short bf16x8;

__device__ __forceinline__ float sigmoidf_(float v) {
    return 1.0f / (1.0f + expf(-v));
}

// async global->LDS, 16B per lane; lptr must be wave-uniform base,
// lane i's data lands at lptr + i*16.
__device__ __forceinline__ void async16(const void* g, void* l) {
    __builtin_amdgcn_global_load_lds(
        (const __attribute__((address_space(1))) unsigned int*)g,
        (__attribute__((address_space(3))) unsigned int*)l,
        16, 0, 0);
}

// ---------------------------------------------------------------------------
// Kernel 1: combined circulant kernel c[n] = sum_m unbind[m] * bind[(m+n)%D]
// (spectrum = BIND * conj(UNBIND))
// grid 4 x 256
__global__ void k_combine(const float* __restrict__ bind,
                          const float* __restrict__ unbind,
                          float* __restrict__ c) {
    __shared__ float sb[Dd];
    __shared__ float su[Dd];
    int t = threadIdx.x;
    for (int j = t; j < Dd; j += 256) { sb[j] = bind[j]; su[j] = unbind[j]; }
    __syncthreads();
    int n = blockIdx.x * 256 + t;
    float acc = 0.f;
    #pragma unroll 8
    for (int m = 0; m < Dd; ++m) acc = fmaf(su[m], sb[(m + n) & (Dd - 1)], acc);
    c[n] = acc;
}

// ---------------------------------------------------------------------------
// Kernel 2: Wt[n][k] = bf16(c[(n-k) mod D]); row-major [1024][1024]
// grid 4096 x 256
__global__ void k_build_w(const float* __restrict__ c,
                          __hip_bfloat16* __restrict__ wt) {
    int idx = blockIdx.x * 256 + threadIdx.x;
    int n = idx >> 10, k = idx & (Dd - 1);
    wt[idx] = __float2bfloat16(c[(n - k) & (Dd - 1)]);
}

// ---------------------------------------------------------------------------
// Kernel 3: per-chunk local EMA end values. endv[b][chunk][i]
// grid 512 x 256 (B*NCHUNK*D threads)
__global__ void k_endvals(const float* __restrict__ x,
                          const float* __restrict__ decay,
                          float* __restrict__ endv) {
    int idx = blockIdx.x * 256 + threadIdx.x;
    int i = idx & (Dd - 1);
    int chunk = (idx >> 10) & (NCHUNK - 1);
    int b = idx >> 15;
    float dd = sigmoidf_(decay[0]);
    const float* xp = x + ((size_t)b * Tt + (size_t)chunk * CLEN) * Dd + i;
    float e = 0.f;
    #pragma unroll 4
    for (int t = 0; t < CLEN; ++t) e = fmaf(dd, e, xp[(size_t)t * Dd]);
    endv[idx] = e;
}

// ---------------------------------------------------------------------------
// Kernel 4: cross-chunk carries. carry[b][chunk][i] = h at end of chunk-1
// grid 16 x 256 (B*D threads)
__global__ void k_carries(const float* __restrict__ endv,
                          const float* __restrict__ decay,
                          float* __restrict__ carry) {
    int idx = blockIdx.x * 256 + threadIdx.x;
    int i = idx & (Dd - 1);
    int b = idx >> 10;
    float dd = sigmoidf_(decay[0]);
    float dL = powf(dd, (float)CLEN);
    float run = 0.f;
    #pragma unroll
    for (int c = 0; c < NCHUNK; ++c) {
        size_t off = ((size_t)b * NCHUNK + c) * Dd + i;
        carry[off] = run;
        run = fmaf(dL, run, endv[off]);
    }
}

// ---------------------------------------------------------------------------
// Kernel 5: apply scan with carry, emit bf16 xs[b][t][i]
// grid 512 x 256
__global__ void k_scan(const float* __restrict__ x,
                       const float* __restrict__ decay,
                       const float* __restrict__ carry,
                       __hip_bfloat16* __restrict__ xs) {
    int idx = blockIdx.x * 256 + threadIdx.x;
    int i = idx & (Dd - 1);
    int chunk = (idx >> 10) & (NCHUNK - 1);
    int b = idx >> 15;
    float dd = sigmoidf_(decay[0]);
    size_t base = ((size_t)b * Tt + (size_t)chunk * CLEN) * Dd + i;
    float h = carry[((size_t)b * NCHUNK + chunk) * Dd + i];
    #pragma unroll 4
    for (int t = 0; t < CLEN; ++t) {
        h = fmaf(dd, h, x[base + (size_t)t * Dd]);
        xs[base + (size_t)t * Dd] = __float2bfloat16(h);
    }
}

// ---------------------------------------------------------------------------
// Kernel 6: out[r][n] = x[r][n] + gate * sum_k xs[r][k] * Wt[n][k]
// 128x128 tile, BK=32, 4 waves in 2x2, 16x16x32 bf16 MFMA, async LDS staging.
// grid (64, 8) x 256
__global__ __launch_bounds__(256) void k_gemm(
    const __hip_bfloat16* __restrict__ A,   // [R][D] bf16 (scanned x)
    const __hip_bfloat16* __restrict__ Wt,  // [D][D] bf16, Wt[n][k]
    const float* __restrict__ x,            // [R][D] fp32
    const float* __restrict__ gate,         // [1]
    float* __restrict__ out)                // [R][D] fp32
{
    __shared__ __align__(16) __hip_bfloat16 sA[128 * 32];
    __shared__ __align__(16) __hip_bfloat16 sB[128 * 32];

    const int tid = threadIdx.x;
    const int wave = tid >> 6;
    const int lane = tid & 63;
    const int tile_m = blockIdx.x * 128;
    const int tile_n = blockIdx.y * 128;
    const int wm = (wave & 1) * 64;
    const int wn = (wave >> 1) * 64;

    f32x4 acc[4][4];
    #pragma unroll
    for (int i = 0; i < 4; ++i)
        #pragma unroll
        for (int j = 0; j < 4; ++j)
            acc[i][j] = (f32x4){0.f, 0.f, 0.f, 0.f};

    const int srow = lane >> 2;        // 0..15: row within 16-row staging group
    const int skk  = (lane & 3) * 8;   // 0,8,16,24: k-element offset (16B chunks)
    const int fr = lane & 15;          // fragment row/col
    const int fk = (lane >> 4) * 8;    // fragment k offset

    for (int k0 = 0; k0 < Dd; k0 += 32) {
        __syncthreads();  // protect LDS from previous iteration's readers
        #pragma unroll
        for (int j = 0; j < 2; ++j) {
            const int row = wave * 32 + j * 16;  // wave-uniform
            async16(A  + (size_t)(tile_m + row + srow) * Dd + k0 + skk, &sA[row * 32]);
            async16(Wt + (size_t)(tile_n + row + srow) * Dd + k0 + skk, &sB[row * 32]);
        }
        __syncthreads();  // compiler emits vmcnt(0) drain before barrier

        bf16x8 af[4], bfr[4];
        #pragma unroll
        for (int mt = 0; mt < 4; ++mt)
            af[mt] = *(const bf16x8*)&sA[(wm + mt * 16 + fr) * 32 + fk];
        #pragma unroll
        for (int nt = 0; nt < 4; ++nt)
            bfr[nt] = *(const bf16x8*)&sB[(wn + nt * 16 + fr) * 32 + fk];

        #pragma unroll
        for (int mt = 0; mt < 4; ++mt)
            #pragma unroll
            for (int nt = 0; nt < 4; ++nt)
                acc[mt][nt] = __builtin_amdgcn_mfma_f32_16x16x32_bf16(
                    af[mt], bfr[nt], acc[mt][nt], 0, 0, 0);
    }

    const float g = gate[0];
    #pragma unroll
    for (int mt = 0; mt < 4; ++mt) {
        const int row0 = tile_m + wm + mt * 16 + (lane >> 4) * 4;
        #pragma unroll
        for (int nt = 0; nt < 4; ++nt) {
            const int col = tile_n + wn + nt * 16 + (lane & 15);
            #pragma unroll
            for (int gg = 0; gg < 4; ++gg) {
                const size_t off = (size_t)(row0 + gg) * Dd + col;
                out[off] = fmaf(g, acc[mt][nt][gg], x[off]);
            }
        }
    }
}

// ---------------------------------------------------------------------------
extern "C" void kernel_launch(void* const* d_in, const int* in_sizes, int n_in,
                              void* d_out, int out_size, void* d_ws, size_t ws_size,
                              hipStream_t stream) {
    const float* x      = (const float*)d_in[0];
    const float* bind   = (const float*)d_in[1];
    const float* unbind = (const float*)d_in[2];
    const float* gate   = (const float*)d_in[3];
    const float* decay  = (const float*)d_in[4];
    float* out = (float*)d_out;

    // workspace layout (~19.3 MB)
    char* ws = (char*)d_ws;
    float* c = (float*)ws;                                             // 4 KB
    __hip_bfloat16* wt = (__hip_bfloat16*)(ws + 4096);                 // 2 MB
    __hip_bfloat16* xs = (__hip_bfloat16*)(ws + 4096 + (size_t)Dd * Dd * 2);  // 16 MB
    char* p3 = ws + 4096 + (size_t)Dd * Dd * 2 + (size_t)Rr * Dd * 2;
    float* endv  = (float*)p3;                                         // 512 KB
    float* carry = endv + (size_t)Bb * NCHUNK * Dd;                    // 512 KB

    k_combine<<<dim3(4),        dim3(256), 0, stream>>>(bind, unbind, c);
    k_build_w<<<dim3(4096),     dim3(256), 0, stream>>>(c, wt);
    k_endvals<<<dim3(512),      dim3(256), 0, stream>>>(x, decay, endv);
    k_carries<<<dim3(16),       dim3(256), 0, stream>>>(endv, decay, carry);
    k_scan<<<dim3(512),         dim3(256), 0, stream>>>(x, decay, carry, xs);
    k_gemm<<<dim3(64, 8),       dim3(256), 0, stream>>>(xs, wt, x, gate, out);
}